// Round 4
// baseline (142.951 us; speedup 1.0000x reference)
//
#include <hip/hip_runtime.h>

#define NB 8192   // batch
#define NC 1024   // controller width (K)
#define NM 4096   // memory size (N)
#define NCH 64    // NM / 64 (64-col chunks per row)

typedef __attribute__((ext_vector_type(8))) short bf16x8;
typedef __attribute__((ext_vector_type(4))) float f32x4;

__device__ __forceinline__ unsigned short f2bf(float x) {
  unsigned int u = __float_as_uint(x);
  u += 0x7FFFu + ((u >> 16) & 1u);
  return (unsigned short)(u >> 16);
}
__device__ __forceinline__ unsigned int pk2(float a, float b) {
  return (unsigned int)f2bf(a) | ((unsigned int)f2bf(b) << 16);
}

__device__ __forceinline__ void gload_lds16(const void* g, void* l) {
  __builtin_amdgcn_global_load_lds(
      (const __attribute__((address_space(1))) unsigned int*)g,
      (__attribute__((address_space(3))) unsigned int*)l, 16, 0, 0);
}

// ---------------- Kernel 0: co [B,C] f32 -> bf16 ----------------
__global__ __launch_bounds__(256) void convA_k(const float* __restrict__ src,
                                               unsigned short* __restrict__ dst) {
  const size_t i = ((size_t)blockIdx.x * 256 + threadIdx.x) * 8;
  const float4* s = reinterpret_cast<const float4*>(src + i);
  float4 x0 = s[0], x1 = s[1];
  int4 o = make_int4((int)pk2(x0.x, x0.y), (int)pk2(x0.z, x0.w),
                     (int)pk2(x1.x, x1.y), (int)pk2(x1.z, x1.w));
  *reinterpret_cast<int4*>(dst + i) = o;
}

// ---------------- Kernel 1: W [K,N] f32 -> Wt [N,K] bf16 ----------------
__global__ __launch_bounds__(256) void convW_k(const float* __restrict__ W,
                                               unsigned short* __restrict__ Wt) {
  __shared__ float tile[64][65];
  const int n0 = blockIdx.x * 64, k0 = blockIdx.y * 64;
  const int t = threadIdx.x;
  const int r = t >> 2, q = t & 3;
  const float4* src = reinterpret_cast<const float4*>(W + (size_t)(k0 + r) * NM + n0 + q * 16);
  float4 x0 = src[0], x1 = src[1], x2 = src[2], x3 = src[3];
  float* tr = &tile[r][q * 16];
  tr[0]=x0.x; tr[1]=x0.y; tr[2]=x0.z;  tr[3]=x0.w;
  tr[4]=x1.x; tr[5]=x1.y; tr[6]=x1.z;  tr[7]=x1.w;
  tr[8]=x2.x; tr[9]=x2.y; tr[10]=x2.z; tr[11]=x2.w;
  tr[12]=x3.x; tr[13]=x3.y; tr[14]=x3.z; tr[15]=x3.w;
  __syncthreads();
  unsigned int pk[8];
#pragma unroll
  for (int i = 0; i < 8; ++i)
    pk[i] = pk2(tile[q * 16 + 2 * i][r], tile[q * 16 + 2 * i + 1][r]);
  int4* dst = reinterpret_cast<int4*>(Wt + (size_t)(n0 + r) * NC + k0 + q * 16);
  dst[0] = make_int4((int)pk[0], (int)pk[1], (int)pk[2], (int)pk[3]);
  dst[1] = make_int4((int)pk[4], (int)pk[5], (int)pk[6], (int)pk[7]);
}

// ------- Kernel 2: bf16 MFMA GEMM (128x128 tile, dbuf global_load_lds,
//         8-slot XOR swizzle) + fused row-partials epilogue -------
__global__ __launch_bounds__(256) void gemm_fused(
    const unsigned short* __restrict__ Abf, const float* __restrict__ memry,
    const unsigned short* __restrict__ Wt, const float* __restrict__ bvec,
    float* __restrict__ pdotg, float* __restrict__ pesqg,
    float* __restrict__ pmsqg, float* __restrict__ pmsg) {
  // double-buffered linear LDS [2][128][32] bf16 (16 KiB each matrix)
  __shared__ __align__(16) unsigned short As[2][128 * 32];
  __shared__ __align__(16) unsigned short Bs[2][128 * 32];
  const int bm = blockIdx.x, bn = blockIdx.y;
  const int row0 = bm * 128, col0 = bn * 128;
  const int t = threadIdx.x;
  const int wid = t >> 6, lane = t & 63;
  const int wr = wid >> 1, wc = wid & 1;
  const int l15 = lane & 15, lg = lane >> 4;

  f32x4 acc[4][4];
#pragma unroll
  for (int mi = 0; mi < 4; ++mi)
#pragma unroll
    for (int ni = 0; ni < 4; ++ni) acc[mi][ni] = (f32x4){0.f, 0.f, 0.f, 0.f};

  // ---- staging (pre-swizzled global source; LDS written linearly) ----
  // thread t writes LDS granule (row=t>>2, gs=t&3); granule (r,gs) must hold
  // k-chunk gs ^ ((r>>1)&3)  => slot (4*(r&1) + gs) is bijective over 8 rows
  const int srow = t >> 2;
  const int scol = ((t & 3) ^ ((srow >> 1) & 3)) * 8;  // same for row+64 (bit5 doesn't hit &3)
  const unsigned short* gA0 = Abf + (size_t)(row0 + srow) * NC + scol;
  const unsigned short* gA1 = Abf + (size_t)(row0 + srow + 64) * NC + scol;
  const unsigned short* gB0 = Wt + (size_t)(col0 + srow) * NC + scol;
  const unsigned short* gB1 = Wt + (size_t)(col0 + srow + 64) * NC + scol;

  // ---- fragment read offsets (halfword units), same XOR on read ----
  const int rowa = wr * 64 + l15;  // + mi*16 (doesn't change (row>>1)&3)
  const int rowb = wc * 64 + l15;
  const int ga = (lg ^ ((l15 >> 1) & 3)) * 8;
  const int gb = ga;

#define STAGE(buf, kt)                                         \
  do {                                                         \
    const int koff = (kt) * 32;                                \
    gload_lds16(gA0 + koff, &As[buf][wid * 512]);              \
    gload_lds16(gA1 + koff, &As[buf][2048 + wid * 512]);       \
    gload_lds16(gB0 + koff, &Bs[buf][wid * 512]);              \
    gload_lds16(gB1 + koff, &Bs[buf][2048 + wid * 512]);       \
  } while (0)

  STAGE(0, 0);
  __syncthreads();  // prologue loads landed (vmcnt0 + barrier)

  for (int kt = 0; kt < 32; ++kt) {
    const int cur = kt & 1;
    if (kt + 1 < 32) STAGE(cur ^ 1, kt + 1);  // issue next-tile loads early

    bf16x8 af[4], bfv[4];
#pragma unroll
    for (int mi = 0; mi < 4; ++mi)
      af[mi] = *reinterpret_cast<const bf16x8*>(&As[cur][(rowa + mi * 16) * 32 + ga]);
#pragma unroll
    for (int ni = 0; ni < 4; ++ni)
      bfv[ni] = *reinterpret_cast<const bf16x8*>(&Bs[cur][(rowb + ni * 16) * 32 + gb]);
#pragma unroll
    for (int mi = 0; mi < 4; ++mi)
#pragma unroll
      for (int ni = 0; ni < 4; ++ni)
        acc[mi][ni] = __builtin_amdgcn_mfma_f32_16x16x32_bf16(af[mi], bfv[ni], acc[mi][ni], 0, 0, 0);

    __syncthreads();  // next-tile loads landed; reads of cur done before re-stage
  }
#undef STAGE

  // epilogue: e = exp(z + b); per-row partials of e*mem, e^2, mem^2, mem
  float bv[4];
#pragma unroll
  for (int ni = 0; ni < 4; ++ni) bv[ni] = bvec[col0 + wc * 64 + ni * 16 + l15];

  const int chunk = bn * 2 + wc;
#pragma unroll
  for (int mi = 0; mi < 4; ++mi) {
#pragma unroll
    for (int j = 0; j < 4; ++j) {
      const int rowm = row0 + wr * 64 + mi * 16 + 4 * lg + j;
      float pd = 0.f, pe = 0.f, pq = 0.f, pm = 0.f;
#pragma unroll
      for (int ni = 0; ni < 4; ++ni) {
        float e = __expf(acc[mi][ni][j] + bv[ni]);
        float mv = memry[(size_t)rowm * NM + col0 + wc * 64 + ni * 16 + l15];
        pd += e * mv; pe += e * e; pq += mv * mv; pm += mv;
      }
#pragma unroll
      for (int s = 1; s < 16; s <<= 1) {
        pd += __shfl_xor(pd, s);
        pe += __shfl_xor(pe, s);
        pq += __shfl_xor(pq, s);
        pm += __shfl_xor(pm, s);
      }
      if (l15 == 0) {
        const int idx = rowm * NCH + chunk;
        pdotg[idx] = pd; pesqg[idx] = pe; pmsqg[idx] = pq; pmsg[idx] = pm;
      }
    }
  }
}

// ---------------- Kernel 3: reduce partials -> sims, msum ----------------
__global__ __launch_bounds__(256) void finalize_k(
    const float* __restrict__ pd, const float* __restrict__ pe,
    const float* __restrict__ pq, const float* __restrict__ pm,
    float* __restrict__ sims, float* __restrict__ mst) {
  const int r = blockIdx.x * 256 + threadIdx.x;
  float d = 0.f, e = 0.f, q = 0.f, m = 0.f;
#pragma unroll
  for (int i = 0; i < NCH; ++i) {
    d += pd[r * NCH + i];
    e += pe[r * NCH + i];
    q += pq[r * NCH + i];
    m += pm[r * NCH + i];
  }
  sims[r] = -d / (sqrtf(fmaxf(e, 1e-12f)) * sqrtf(fmaxf(q, 1e-12f)));
  mst[r] = m;
}

// ------------- Kernel 4: softmax over B=8192 + final scaling -------------
__global__ __launch_bounds__(1024) void softmax_out_k(
    const float* __restrict__ sims, const float* __restrict__ mst,
    float* __restrict__ out) {
  __shared__ float red[16];
  const int t = threadIdx.x;
  float v[8];
  float mx = -1e30f;
#pragma unroll
  for (int i = 0; i < 8; ++i) {
    v[i] = sims[t + i * 1024];
    mx = fmaxf(mx, v[i]);
  }
#pragma unroll
  for (int s = 1; s < 64; s <<= 1) mx = fmaxf(mx, __shfl_xor(mx, s));
  if ((t & 63) == 0) red[t >> 6] = mx;
  __syncthreads();
  float m2 = red[0];
#pragma unroll
  for (int i = 1; i < 16; ++i) m2 = fmaxf(m2, red[i]);
  mx = m2;
  float sum = 0.f;
#pragma unroll
  for (int i = 0; i < 8; ++i) sum += __expf(v[i] - mx);
#pragma unroll
  for (int s = 1; s < 64; s <<= 1) sum += __shfl_xor(sum, s);
  __syncthreads();
  if ((t & 63) == 0) red[t >> 6] = sum;
  __syncthreads();
  float s2 = 0.f;
#pragma unroll
  for (int i = 0; i < 16; ++i) s2 += red[i];
  const float inv = 1.0f / s2;
#pragma unroll
  for (int i = 0; i < 8; ++i)
    out[t + i * 1024] = __expf(v[i] - mx) * inv * mst[t + i * 1024];
}

extern "C" void kernel_launch(void* const* d_in, const int* in_sizes, int n_in,
                              void* d_out, int out_size, void* d_ws, size_t ws_size,
                              hipStream_t stream) {
  const float* memry = (const float*)d_in[0];  // [B, M]
  const float* co    = (const float*)d_in[1];  // [B, C]
  const float* W     = (const float*)d_in[2];  // [C, M]
  const float* bvec  = (const float*)d_in[3];  // [M]
  float* out = (float*)d_out;                  // [B]

  char* w = (char*)d_ws;
  unsigned short* Wt  = (unsigned short*)w;                       // 8 MiB
  unsigned short* Abf = Wt + (size_t)NM * NC;                     // 16 MiB
  float* pdot = (float*)(Abf + (size_t)NB * NC);                  // 8192*64 f32 each
  float* pesq = pdot + (size_t)NB * NCH;
  float* pmsq = pesq + (size_t)NB * NCH;
  float* pms  = pmsq + (size_t)NB * NCH;
  float* sims = pms  + (size_t)NB * NCH;
  float* mst  = sims + NB;

  convA_k<<<(size_t)NB * NC / (256 * 8), 256, 0, stream>>>(co, Abf);
  convW_k<<<dim3(NM / 64, NC / 64), 256, 0, stream>>>(W, Wt);
  gemm_fused<<<dim3(NB / 128, NM / 128), 256, 0, stream>>>(Abf, memry, Wt, bvec,
                                                           pdot, pesq, pmsq, pms);
  finalize_k<<<NB / 256, 256, 0, stream>>>(pdot, pesq, pmsq, pms, sims, mst);
  softmax_out_k<<<1, 1024, 0, stream>>>(sims, mst, out);
}

// Round 5
// 126.555 us; speedup vs baseline: 1.1296x; 1.1296x over previous
//
#include <hip/hip_runtime.h>

#define NB 8192   // batch
#define NC 1024   // controller width (K)
#define NM 4096   // memory size (N)
#define NCH 64    // NM / 64 (64-col chunks per row)

typedef __attribute__((ext_vector_type(8))) short bf16x8;
typedef __attribute__((ext_vector_type(4))) float f32x4;

__device__ __forceinline__ unsigned short f2bf(float x) {
  unsigned int u = __float_as_uint(x);
  u += 0x7FFFu + ((u >> 16) & 1u);
  return (unsigned short)(u >> 16);
}
__device__ __forceinline__ unsigned int pk2(float a, float b) {
  return (unsigned int)f2bf(a) | ((unsigned int)f2bf(b) << 16);
}

__device__ __forceinline__ void gload_lds16(const void* g, void* l) {
  __builtin_amdgcn_global_load_lds(
      (const __attribute__((address_space(1))) unsigned int*)g,
      (__attribute__((address_space(3))) unsigned int*)l, 16, 0, 0);
}

// ---------------- Kernel 0: co [B,C] f32 -> bf16 ----------------
__global__ __launch_bounds__(256) void convA_k(const float* __restrict__ src,
                                               unsigned short* __restrict__ dst) {
  const size_t i = ((size_t)blockIdx.x * 256 + threadIdx.x) * 8;
  const float4* s = reinterpret_cast<const float4*>(src + i);
  float4 x0 = s[0], x1 = s[1];
  int4 o = make_int4((int)pk2(x0.x, x0.y), (int)pk2(x0.z, x0.w),
                     (int)pk2(x1.x, x1.y), (int)pk2(x1.z, x1.w));
  *reinterpret_cast<int4*>(dst + i) = o;
}

// ---------------- Kernel 1: W [K,N] f32 -> Wt [N,K] bf16 ----------------
__global__ __launch_bounds__(256) void convW_k(const float* __restrict__ W,
                                               unsigned short* __restrict__ Wt) {
  __shared__ float tile[64][65];
  const int n0 = blockIdx.x * 64, k0 = blockIdx.y * 64;
  const int t = threadIdx.x;
  const int r = t >> 2, q = t & 3;
  const float4* src = reinterpret_cast<const float4*>(W + (size_t)(k0 + r) * NM + n0 + q * 16);
  float4 x0 = src[0], x1 = src[1], x2 = src[2], x3 = src[3];
  float* tr = &tile[r][q * 16];
  tr[0]=x0.x; tr[1]=x0.y; tr[2]=x0.z;  tr[3]=x0.w;
  tr[4]=x1.x; tr[5]=x1.y; tr[6]=x1.z;  tr[7]=x1.w;
  tr[8]=x2.x; tr[9]=x2.y; tr[10]=x2.z; tr[11]=x2.w;
  tr[12]=x3.x; tr[13]=x3.y; tr[14]=x3.z; tr[15]=x3.w;
  __syncthreads();
  unsigned int pk[8];
#pragma unroll
  for (int i = 0; i < 8; ++i)
    pk[i] = pk2(tile[q * 16 + 2 * i][r], tile[q * 16 + 2 * i + 1][r]);
  int4* dst = reinterpret_cast<int4*>(Wt + (size_t)(n0 + r) * NC + k0 + q * 16);
  dst[0] = make_int4((int)pk[0], (int)pk[1], (int)pk[2], (int)pk[3]);
  dst[1] = make_int4((int)pk[4], (int)pk[5], (int)pk[6], (int)pk[7]);
}

// ------- Kernel 2: 256x256-tile 8-phase bf16 MFMA GEMM (T2+T3+T4+T5)
//         + fused row-partials epilogue -------
// 8 waves (2M x 4N), BK=64 split into two k-halves of 32.
// Half-buffers (16 KB each): LDS[slot][type][8192], type 0=Ak0 1=Ak1 2=Bk0 3=Bk1.
// Stage: linear dest (uniform base + lane*16B), pre-swizzled global source
// kg = (t&3) ^ ((t>>2>>1)&3); read applies the same XOR (rule #21).
__global__ __launch_bounds__(512) void gemm_fused(
    const unsigned short* __restrict__ Abf, const float* __restrict__ memry,
    const unsigned short* __restrict__ Wt, const float* __restrict__ bvec,
    float* __restrict__ pdotg, float* __restrict__ pesqg,
    float* __restrict__ pmsqg, float* __restrict__ pmsg) {
  __shared__ __align__(16) unsigned short LDS[2][4][8192];  // 128 KiB
  const int bm = blockIdx.x, bn = blockIdx.y;
  const int row0 = bm * 256, col0 = bn * 256;
  const int t = threadIdx.x;
  const int wid = t >> 6, lane = t & 63;
  const int wr = wid >> 2, wc = wid & 3;          // 2 x 4 waves
  const int l15 = lane & 15, lg = lane >> 4;
  const int ga8 = (lg ^ ((l15 >> 1) & 3)) * 8;    // swizzled k-granule (halfwords)

  f32x4 acc[8][4];
#pragma unroll
  for (int mi = 0; mi < 8; ++mi)
#pragma unroll
    for (int ni = 0; ni < 4; ++ni) acc[mi][ni] = (f32x4){0.f, 0.f, 0.f, 0.f};

  // staging source (pre-swizzled column granule; same for row and row+128)
  const int srow0 = t >> 2;
  const int sk8 = ((t & 3) ^ ((srow0 >> 1) & 3)) * 8;
  const unsigned short* gA = Abf + (size_t)(row0 + srow0) * NC + sk8;
  const unsigned short* gB = Wt + (size_t)(col0 + srow0) * NC + sk8;

#define STG(SL, TY, KT)                                                      \
  {                                                                          \
    const unsigned short* s0 = ((TY) <= 1 ? gA : gB) + (KT) * 64 + ((TY)&1) * 32; \
    gload_lds16(s0, &LDS[SL][TY][t * 8]);                                    \
    gload_lds16(s0 + (size_t)128 * NC, &LDS[SL][TY][t * 8 + 4096]);          \
  }
#define NOSTG
#define VM6 asm volatile("s_waitcnt vmcnt(6)" ::: "memory")
#define VM0 asm volatile("s_waitcnt vmcnt(0)" ::: "memory")
#define NOVM

  // phase: ds-reads -> stage issue -> [vmcnt] -> barrier -> MFMA cluster -> barrier
#define PH(SL, S, MH, RDB, STAGE, VM)                                        \
  {                                                                          \
    if (RDB) {                                                               \
      _Pragma("unroll") for (int ni = 0; ni < 4; ++ni)                       \
          b[ni] = *reinterpret_cast<const bf16x8*>(                          \
              &LDS[SL][2 + (S)][(wc * 64 + ni * 16 + l15) * 32 + ga8]);      \
    }                                                                        \
    _Pragma("unroll") for (int mi = 0; mi < 4; ++mi)                         \
        a[mi] = *reinterpret_cast<const bf16x8*>(                            \
            &LDS[SL][S][(wr * 128 + (MH)*64 + mi * 16 + l15) * 32 + ga8]);   \
    STAGE;                                                                   \
    VM;                                                                      \
    __builtin_amdgcn_s_barrier();                                            \
    __builtin_amdgcn_sched_barrier(0);                                       \
    __builtin_amdgcn_s_setprio(1);                                           \
    _Pragma("unroll") for (int mi = 0; mi < 4; ++mi)                         \
        _Pragma("unroll") for (int ni = 0; ni < 4; ++ni)                     \
            acc[(MH)*4 + mi][ni] = __builtin_amdgcn_mfma_f32_16x16x32_bf16(  \
                a[mi], b[ni], acc[(MH)*4 + mi][ni], 0, 0, 0);                \
    __builtin_amdgcn_s_setprio(0);                                           \
    __builtin_amdgcn_s_barrier();                                            \
    __builtin_amdgcn_sched_barrier(0);                                       \
  }

  // ---- prologue: K-tile 0 fully + K-tile 1 minus Ak1 (vmcnt(6) -> c0 landed)
  STG(0, 2, 0); STG(0, 0, 0); STG(0, 3, 0); STG(0, 1, 0);
  STG(1, 2, 1); STG(1, 0, 1); STG(1, 3, 1);
  VM6;
  __builtin_amdgcn_s_barrier();
  __builtin_amdgcn_sched_barrier(0);

  bf16x8 a[4], b[4];
  // ---- main loop: 7 iterations x 2 K-tiles (K-tiles 0..13 computed here)
  for (int it = 0; it < 7; ++it) {
    const int c1 = 2 * it + 1, c2 = 2 * it + 2, c3 = 2 * it + 3;
    PH(0, 0, 0, true,  STG(1, 1, c1), NOVM);  // ph1
    PH(0, 0, 1, false, STG(0, 2, c2), NOVM);  // ph2
    PH(0, 1, 0, true,  STG(0, 0, c2), NOVM);  // ph3
    PH(0, 1, 1, false, STG(0, 3, c2), VM6);   // ph4
    PH(1, 0, 0, true,  STG(0, 1, c2), NOVM);  // ph5
    PH(1, 0, 1, false, STG(1, 2, c3), NOVM);  // ph6
    PH(1, 1, 0, true,  STG(1, 0, c3), NOVM);  // ph7
    PH(1, 1, 1, false, STG(1, 3, c3), VM6);   // ph8
  }
  // ---- final iteration (K-tiles 14, 15): only Ak1(15) left to stage
  PH(0, 0, 0, true,  STG(1, 1, 15), NOVM);
  PH(0, 0, 1, false, NOSTG, NOVM);
  PH(0, 1, 0, true,  NOSTG, NOVM);
  PH(0, 1, 1, false, NOSTG, VM0);
  PH(1, 0, 0, true,  NOSTG, NOVM);
  PH(1, 0, 1, false, NOSTG, NOVM);
  PH(1, 1, 0, true,  NOSTG, NOVM);
  PH(1, 1, 1, false, NOSTG, NOVM);
#undef PH
#undef STG

  // ---- epilogue: e = exp(z + b); per-row partials of e*mem, e^2, mem^2, mem
  float bv[4];
#pragma unroll
  for (int ni = 0; ni < 4; ++ni) bv[ni] = bvec[col0 + wc * 64 + ni * 16 + l15];

  const int chunk = bn * 4 + wc;
#pragma unroll
  for (int mi = 0; mi < 8; ++mi) {
#pragma unroll
    for (int j = 0; j < 4; ++j) {
      const int rowm = row0 + wr * 128 + mi * 16 + 4 * lg + j;
      float pd = 0.f, pe = 0.f, pq = 0.f, pm = 0.f;
#pragma unroll
      for (int ni = 0; ni < 4; ++ni) {
        float e = __expf(acc[mi][ni][j] + bv[ni]);
        float mv = memry[(size_t)rowm * NM + col0 + wc * 64 + ni * 16 + l15];
        pd += e * mv; pe += e * e; pq += mv * mv; pm += mv;
      }
#pragma unroll
      for (int s = 1; s < 16; s <<= 1) {
        pd += __shfl_xor(pd, s);
        pe += __shfl_xor(pe, s);
        pq += __shfl_xor(pq, s);
        pm += __shfl_xor(pm, s);
      }
      if (l15 == 0) {
        const int idx = rowm * NCH + chunk;
        pdotg[idx] = pd; pesqg[idx] = pe; pmsqg[idx] = pq; pmsg[idx] = pm;
      }
    }
  }
}

// ---------------- Kernel 3: reduce partials -> sims, msum ----------------
__global__ __launch_bounds__(256) void finalize_k(
    const float* __restrict__ pd, const float* __restrict__ pe,
    const float* __restrict__ pq, const float* __restrict__ pm,
    float* __restrict__ sims, float* __restrict__ mst) {
  const int r = blockIdx.x * 256 + threadIdx.x;
  float d = 0.f, e = 0.f, q = 0.f, m = 0.f;
#pragma unroll
  for (int i = 0; i < NCH; ++i) {
    d += pd[r * NCH + i];
    e += pe[r * NCH + i];
    q += pq[r * NCH + i];
    m += pm[r * NCH + i];
  }
  sims[r] = -d / (sqrtf(fmaxf(e, 1e-12f)) * sqrtf(fmaxf(q, 1e-12f)));
  mst[r] = m;
}

// ------------- Kernel 4: softmax over B=8192 + final scaling -------------
__global__ __launch_bounds__(1024) void softmax_out_k(
    const float* __restrict__ sims, const float* __restrict__ mst,
    float* __restrict__ out) {
  __shared__ float red[16];
  const int t = threadIdx.x;
  float v[8];
  float mx = -1e30f;
#pragma unroll
  for (int i = 0; i < 8; ++i) {
    v[i] = sims[t + i * 1024];
    mx = fmaxf(mx, v[i]);
  }
#pragma unroll
  for (int s = 1; s < 64; s <<= 1) mx = fmaxf(mx, __shfl_xor(mx, s));
  if ((t & 63) == 0) red[t >> 6] = mx;
  __syncthreads();
  float m2 = red[0];
#pragma unroll
  for (int i = 1; i < 16; ++i) m2 = fmaxf(m2, red[i]);
  mx = m2;
  float sum = 0.f;
#pragma unroll
  for (int i = 0; i < 8; ++i) sum += __expf(v[i] - mx);
#pragma unroll
  for (int s = 1; s < 64; s <<= 1) sum += __shfl_xor(sum, s);
  __syncthreads();
  if ((t & 63) == 0) red[t >> 6] = sum;
  __syncthreads();
  float s2 = 0.f;
#pragma unroll
  for (int i = 0; i < 16; ++i) s2 += red[i];
  const float inv = 1.0f / s2;
#pragma unroll
  for (int i = 0; i < 8; ++i)
    out[t + i * 1024] = __expf(v[i] - mx) * inv * mst[t + i * 1024];
}

extern "C" void kernel_launch(void* const* d_in, const int* in_sizes, int n_in,
                              void* d_out, int out_size, void* d_ws, size_t ws_size,
                              hipStream_t stream) {
  const float* memry = (const float*)d_in[0];  // [B, M]
  const float* co    = (const float*)d_in[1];  // [B, C]
  const float* W     = (const float*)d_in[2];  // [C, M]
  const float* bvec  = (const float*)d_in[3];  // [M]
  float* out = (float*)d_out;                  // [B]

  char* w = (char*)d_ws;
  unsigned short* Wt  = (unsigned short*)w;                       // 8 MiB
  unsigned short* Abf = Wt + (size_t)NM * NC;                     // 16 MiB
  float* pdot = (float*)(Abf + (size_t)NB * NC);                  // 8192*64 f32 each
  float* pesq = pdot + (size_t)NB * NCH;
  float* pmsq = pesq + (size_t)NB * NCH;
  float* pms  = pmsq + (size_t)NB * NCH;
  float* sims = pms  + (size_t)NB * NCH;
  float* mst  = sims + NB;

  convA_k<<<(size_t)NB * NC / (256 * 8), 256, 0, stream>>>(co, Abf);
  convW_k<<<dim3(NM / 64, NC / 64), 256, 0, stream>>>(W, Wt);
  gemm_fused<<<dim3(NB / 256, NM / 256), 512, 0, stream>>>(Abf, memry, Wt, bvec,
                                                           pdot, pesq, pmsq, pms);
  finalize_k<<<NB / 256, 256, 0, stream>>>(pdot, pesq, pmsq, pms, sims, mst);
  softmax_out_k<<<1, 1024, 0, stream>>>(sims, mst, out);
}

// Round 6
// 109.343 us; speedup vs baseline: 1.3074x; 1.1574x over previous
//
#include <hip/hip_runtime.h>

#define NB 8192   // batch
#define NC 1024   // controller width (K)
#define NM 4096   // memory size (N)
#define NCH 16    // NM / 256 (256-col chunks per row)

typedef __attribute__((ext_vector_type(8))) short bf16x8;
typedef __attribute__((ext_vector_type(4))) float f32x4;

__device__ __forceinline__ unsigned short f2bf(float x) {
  unsigned int u = __float_as_uint(x);
  u += 0x7FFFu + ((u >> 16) & 1u);
  return (unsigned short)(u >> 16);
}
__device__ __forceinline__ unsigned int pk2(float a, float b) {
  return (unsigned int)f2bf(a) | ((unsigned int)f2bf(b) << 16);
}

__device__ __forceinline__ void gload_lds16(const void* g, void* l) {
  __builtin_amdgcn_global_load_lds(
      (const __attribute__((address_space(1))) unsigned int*)g,
      (__attribute__((address_space(3))) unsigned int*)l, 16, 0, 0);
}

// ---------------- Kernel 0: co [B,C] f32 -> bf16 ----------------
__global__ __launch_bounds__(256) void convA_k(const float* __restrict__ src,
                                               unsigned short* __restrict__ dst) {
  const size_t i = ((size_t)blockIdx.x * 256 + threadIdx.x) * 8;
  const float4* s = reinterpret_cast<const float4*>(src + i);
  float4 x0 = s[0], x1 = s[1];
  int4 o = make_int4((int)pk2(x0.x, x0.y), (int)pk2(x0.z, x0.w),
                     (int)pk2(x1.x, x1.y), (int)pk2(x1.z, x1.w));
  *reinterpret_cast<int4*>(dst + i) = o;
}

// ---------------- Kernel 1: W [K,N] f32 -> Wt [N,K] bf16 ----------------
__global__ __launch_bounds__(256) void convW_k(const float* __restrict__ W,
                                               unsigned short* __restrict__ Wt) {
  __shared__ float tile[64][65];
  const int n0 = blockIdx.x * 64, k0 = blockIdx.y * 64;
  const int t = threadIdx.x;
  const int r = t >> 2, q = t & 3;
  const float4* src = reinterpret_cast<const float4*>(W + (size_t)(k0 + r) * NM + n0 + q * 16);
  float4 x0 = src[0], x1 = src[1], x2 = src[2], x3 = src[3];
  float* tr = &tile[r][q * 16];
  tr[0]=x0.x; tr[1]=x0.y; tr[2]=x0.z;  tr[3]=x0.w;
  tr[4]=x1.x; tr[5]=x1.y; tr[6]=x1.z;  tr[7]=x1.w;
  tr[8]=x2.x; tr[9]=x2.y; tr[10]=x2.z; tr[11]=x2.w;
  tr[12]=x3.x; tr[13]=x3.y; tr[14]=x3.z; tr[15]=x3.w;
  __syncthreads();
  unsigned int pk[8];
#pragma unroll
  for (int i = 0; i < 8; ++i)
    pk[i] = pk2(tile[q * 16 + 2 * i][r], tile[q * 16 + 2 * i + 1][r]);
  int4* dst = reinterpret_cast<int4*>(Wt + (size_t)(n0 + r) * NC + k0 + q * 16);
  dst[0] = make_int4((int)pk[0], (int)pk[1], (int)pk[2], (int)pk[3]);
  dst[1] = make_int4((int)pk[4], (int)pk[5], (int)pk[6], (int)pk[7]);
}

// ------- Kernel 2: 256x256-tile 8-phase bf16 MFMA GEMM (T2+T3+T4+T5)
//         + two-phase fused epilogue (e->LDS bf16, coalesced memry pass) -------
__global__ __launch_bounds__(512) void gemm_fused(
    const unsigned short* __restrict__ Abf, const float* __restrict__ memry,
    const unsigned short* __restrict__ Wt, const float* __restrict__ bvec,
    float* __restrict__ pdotg, float* __restrict__ pesqg,
    float* __restrict__ pmsqg, float* __restrict__ pmsg) {
  __shared__ __align__(16) unsigned short LDS[2][4][8192];  // 128 KiB
  const int bm = blockIdx.x, bn = blockIdx.y;
  const int row0 = bm * 256, col0 = bn * 256;
  const int t = threadIdx.x;
  const int wid = t >> 6, lane = t & 63;
  const int wr = wid >> 2, wc = wid & 3;          // 2 x 4 waves
  const int l15 = lane & 15, lg = lane >> 4;
  const int ga8 = (lg ^ ((l15 >> 1) & 3)) * 8;    // swizzled k-granule (halfwords)

  f32x4 acc[8][4];
#pragma unroll
  for (int mi = 0; mi < 8; ++mi)
#pragma unroll
    for (int ni = 0; ni < 4; ++ni) acc[mi][ni] = (f32x4){0.f, 0.f, 0.f, 0.f};

  // staging source (pre-swizzled column granule; same for row and row+128)
  const int srow0 = t >> 2;
  const int sk8 = ((t & 3) ^ ((srow0 >> 1) & 3)) * 8;
  const unsigned short* gA = Abf + (size_t)(row0 + srow0) * NC + sk8;
  const unsigned short* gB = Wt + (size_t)(col0 + srow0) * NC + sk8;

#define STG(SL, TY, KT)                                                      \
  {                                                                          \
    const unsigned short* s0 = ((TY) <= 1 ? gA : gB) + (KT) * 64 + ((TY)&1) * 32; \
    gload_lds16(s0, &LDS[SL][TY][t * 8]);                                    \
    gload_lds16(s0 + (size_t)128 * NC, &LDS[SL][TY][t * 8 + 4096]);          \
  }
#define NOSTG
#define VM6 asm volatile("s_waitcnt vmcnt(6)" ::: "memory")
#define VM0 asm volatile("s_waitcnt vmcnt(0)" ::: "memory")
#define NOVM

  // phase: ds-reads -> stage issue -> [vmcnt] -> barrier -> MFMA cluster -> barrier
#define PH(SL, S, MH, RDB, STAGE, VM)                                        \
  {                                                                          \
    if (RDB) {                                                               \
      _Pragma("unroll") for (int ni = 0; ni < 4; ++ni)                       \
          b[ni] = *reinterpret_cast<const bf16x8*>(                          \
              &LDS[SL][2 + (S)][(wc * 64 + ni * 16 + l15) * 32 + ga8]);      \
    }                                                                        \
    _Pragma("unroll") for (int mi = 0; mi < 4; ++mi)                         \
        a[mi] = *reinterpret_cast<const bf16x8*>(                            \
            &LDS[SL][S][(wr * 128 + (MH)*64 + mi * 16 + l15) * 32 + ga8]);   \
    STAGE;                                                                   \
    VM;                                                                      \
    __builtin_amdgcn_s_barrier();                                            \
    __builtin_amdgcn_sched_barrier(0);                                       \
    __builtin_amdgcn_s_setprio(1);                                           \
    _Pragma("unroll") for (int mi = 0; mi < 4; ++mi)                         \
        _Pragma("unroll") for (int ni = 0; ni < 4; ++ni)                     \
            acc[(MH)*4 + mi][ni] = __builtin_amdgcn_mfma_f32_16x16x32_bf16(  \
                a[mi], b[ni], acc[(MH)*4 + mi][ni], 0, 0, 0);                \
    __builtin_amdgcn_s_setprio(0);                                           \
    __builtin_amdgcn_s_barrier();                                            \
    __builtin_amdgcn_sched_barrier(0);                                       \
  }

  // ---- prologue: K-tile 0 fully + K-tile 1 minus Ak1 (vmcnt(6) -> c0 landed)
  STG(0, 2, 0); STG(0, 0, 0); STG(0, 3, 0); STG(0, 1, 0);
  STG(1, 2, 1); STG(1, 0, 1); STG(1, 3, 1);
  VM6;
  __builtin_amdgcn_s_barrier();
  __builtin_amdgcn_sched_barrier(0);

  bf16x8 a[4], b[4];
  // ---- main loop: 7 iterations x 2 K-tiles (K-tiles 0..13 computed here)
  for (int it = 0; it < 7; ++it) {
    const int c1 = 2 * it + 1, c2 = 2 * it + 2, c3 = 2 * it + 3;
    PH(0, 0, 0, true,  STG(1, 1, c1), NOVM);  // ph1
    PH(0, 0, 1, false, STG(0, 2, c2), NOVM);  // ph2
    PH(0, 1, 0, true,  STG(0, 0, c2), NOVM);  // ph3
    PH(0, 1, 1, false, STG(0, 3, c2), VM6);   // ph4
    PH(1, 0, 0, true,  STG(0, 1, c2), NOVM);  // ph5
    PH(1, 0, 1, false, STG(1, 2, c3), NOVM);  // ph6
    PH(1, 1, 0, true,  STG(1, 0, c3), NOVM);  // ph7
    PH(1, 1, 1, false, STG(1, 3, c3), VM6);   // ph8
  }
  // ---- final iteration (K-tiles 14, 15): only Ak1(15) left to stage
  PH(0, 0, 0, true,  STG(1, 1, 15), NOVM);
  PH(0, 0, 1, false, NOSTG, NOVM);
  PH(0, 1, 0, true,  NOSTG, NOVM);
  PH(0, 1, 1, false, NOSTG, VM0);
  PH(1, 0, 0, true,  NOSTG, NOVM);
  PH(1, 0, 1, false, NOSTG, NOVM);
  PH(1, 1, 0, true,  NOSTG, NOVM);
  PH(1, 1, 1, false, NOSTG, NOVM);
#undef PH
#undef STG

  // ---- E1: e = exp(z + b) -> bf16 into LDS [256][256] (reuses staging LDS;
  //      safe: final phase barrier guarantees all LDS reads are consumed) ----
  unsigned short (*e_lds)[256] = reinterpret_cast<unsigned short(*)[256]>(&LDS[0][0][0]);
  float bv[4];
#pragma unroll
  for (int ni = 0; ni < 4; ++ni) bv[ni] = bvec[col0 + wc * 64 + ni * 16 + l15];
#pragma unroll
  for (int mi = 0; mi < 8; ++mi)
#pragma unroll
    for (int ni = 0; ni < 4; ++ni)
#pragma unroll
      for (int j = 0; j < 4; ++j) {
        const int rl = wr * 128 + mi * 16 + 4 * lg + j;
        const int cl = wc * 64 + ni * 16 + l15;
        e_lds[rl][cl] = f2bf(__expf(acc[mi][ni][j] + bv[ni]));
      }
  __syncthreads();

  // ---- E2: coalesced fused pass: per row, partials of e*m, e^2, m^2, m ----
  {
    const int halfl = lane >> 5, l31 = lane & 31;
    const int rbase = wid * 32;  // each wave owns 32 consecutive rows
#pragma unroll 4
    for (int i = 0; i < 16; ++i) {
      const int rl = rbase + 2 * i + halfl;
      const float4* mp = reinterpret_cast<const float4*>(
          memry + (size_t)(row0 + rl) * NM + col0 + l31 * 8);
      float4 m0 = mp[0], m1 = mp[1];
      bf16x8 ev = *reinterpret_cast<const bf16x8*>(&e_lds[rl][l31 * 8]);
      float mv[8] = {m0.x, m0.y, m0.z, m0.w, m1.x, m1.y, m1.z, m1.w};
      float pd = 0.f, pe = 0.f, pq = 0.f, pm = 0.f;
#pragma unroll
      for (int k = 0; k < 8; ++k) {
        float e = __uint_as_float(((unsigned int)(unsigned short)ev[k]) << 16);
        pd += e * mv[k]; pe += e * e; pq += mv[k] * mv[k]; pm += mv[k];
      }
#pragma unroll
      for (int s = 1; s < 32; s <<= 1) {
        pd += __shfl_xor(pd, s); pe += __shfl_xor(pe, s);
        pq += __shfl_xor(pq, s); pm += __shfl_xor(pm, s);
      }
      if (l31 == 0) {
        const int idx = (row0 + rl) * NCH + bn;
        pdotg[idx] = pd; pesqg[idx] = pe; pmsqg[idx] = pq; pmsg[idx] = pm;
      }
    }
  }
}

// ---------------- Kernel 3: reduce partials -> sims, msum ----------------
__global__ __launch_bounds__(256) void finalize_k(
    const float* __restrict__ pd, const float* __restrict__ pe,
    const float* __restrict__ pq, const float* __restrict__ pm,
    float* __restrict__ sims, float* __restrict__ mst) {
  const int r = blockIdx.x * 256 + threadIdx.x;
  float d = 0.f, e = 0.f, q = 0.f, m = 0.f;
#pragma unroll
  for (int i = 0; i < NCH; ++i) {
    d += pd[r * NCH + i];
    e += pe[r * NCH + i];
    q += pq[r * NCH + i];
    m += pm[r * NCH + i];
  }
  sims[r] = -d / (sqrtf(fmaxf(e, 1e-12f)) * sqrtf(fmaxf(q, 1e-12f)));
  mst[r] = m;
}

// ------------- Kernel 4: softmax over B=8192 + final scaling -------------
__global__ __launch_bounds__(1024) void softmax_out_k(
    const float* __restrict__ sims, const float* __restrict__ mst,
    float* __restrict__ out) {
  __shared__ float red[16];
  const int t = threadIdx.x;
  float v[8];
  float mx = -1e30f;
#pragma unroll
  for (int i = 0; i < 8; ++i) {
    v[i] = sims[t + i * 1024];
    mx = fmaxf(mx, v[i]);
  }
#pragma unroll
  for (int s = 1; s < 64; s <<= 1) mx = fmaxf(mx, __shfl_xor(mx, s));
  if ((t & 63) == 0) red[t >> 6] = mx;
  __syncthreads();
  float m2 = red[0];
#pragma unroll
  for (int i = 1; i < 16; ++i) m2 = fmaxf(m2, red[i]);
  mx = m2;
  float sum = 0.f;
#pragma unroll
  for (int i = 0; i < 8; ++i) sum += __expf(v[i] - mx);
#pragma unroll
  for (int s = 1; s < 64; s <<= 1) sum += __shfl_xor(sum, s);
  __syncthreads();
  if ((t & 63) == 0) red[t >> 6] = sum;
  __syncthreads();
  float s2 = 0.f;
#pragma unroll
  for (int i = 0; i < 16; ++i) s2 += red[i];
  const float inv = 1.0f / s2;
#pragma unroll
  for (int i = 0; i < 8; ++i)
    out[t + i * 1024] = __expf(v[i] - mx) * inv * mst[t + i * 1024];
}

extern "C" void kernel_launch(void* const* d_in, const int* in_sizes, int n_in,
                              void* d_out, int out_size, void* d_ws, size_t ws_size,
                              hipStream_t stream) {
  const float* memry = (const float*)d_in[0];  // [B, M]
  const float* co    = (const float*)d_in[1];  // [B, C]
  const float* W     = (const float*)d_in[2];  // [C, M]
  const float* bvec  = (const float*)d_in[3];  // [M]
  float* out = (float*)d_out;                  // [B]

  char* w = (char*)d_ws;
  unsigned short* Wt  = (unsigned short*)w;                       // 8 MiB
  unsigned short* Abf = Wt + (size_t)NM * NC;                     // 16 MiB
  float* pdot = (float*)(Abf + (size_t)NB * NC);                  // 8192*16 f32 each
  float* pesq = pdot + (size_t)NB * NCH;
  float* pmsq = pesq + (size_t)NB * NCH;
  float* pms  = pmsq + (size_t)NB * NCH;
  float* sims = pms  + (size_t)NB * NCH;
  float* mst  = sims + NB;

  convA_k<<<(size_t)NB * NC / (256 * 8), 256, 0, stream>>>(co, Abf);
  convW_k<<<dim3(NM / 64, NC / 64), 256, 0, stream>>>(W, Wt);
  gemm_fused<<<dim3(NB / 256, NM / 256), 512, 0, stream>>>(Abf, memry, Wt, bvec,
                                                           pdot, pesq, pmsq, pms);
  finalize_k<<<NB / 256, 256, 0, stream>>>(pdot, pesq, pmsq, pms, sims, mst);
  softmax_out_k<<<1, 1024, 0, stream>>>(sims, mst, out);
}

// Round 8
// 109.149 us; speedup vs baseline: 1.3097x; 1.0018x over previous
//
#include <hip/hip_runtime.h>

#define NB 8192   // batch
#define NC 1024   // controller width (K)
#define NM 4096   // memory size (N)
#define NCH 16    // NM / 256 (256-col chunks per row)

typedef __attribute__((ext_vector_type(8))) short bf16x8;
typedef __attribute__((ext_vector_type(4))) float f32x4;

__device__ __forceinline__ unsigned short f2bf(float x) {
  unsigned int u = __float_as_uint(x);
  u += 0x7FFFu + ((u >> 16) & 1u);
  return (unsigned short)(u >> 16);
}
__device__ __forceinline__ unsigned int pk2(float a, float b) {
  return (unsigned int)f2bf(a) | ((unsigned int)f2bf(b) << 16);
}

__device__ __forceinline__ void gload_lds16(const void* g, void* l) {
  __builtin_amdgcn_global_load_lds(
      (const __attribute__((address_space(1))) unsigned int*)g,
      (__attribute__((address_space(3))) unsigned int*)l, 16, 0, 0);
}

// inline-asm ds_read_b128: opaque to the compiler's LDS-alias tracking, so it
// does NOT force vmcnt(0) drains against outstanding global_load_lds (rule #18
// fence applied at use site).
#define DSR(dst, addr, IMM) \
  asm volatile("ds_read_b128 %0, %1 offset:" IMM : "=v"(dst) : "v"(addr))

// ---------------- Kernel 0: co [B,C] f32 -> bf16 ----------------
__global__ __launch_bounds__(256) void convA_k(const float* __restrict__ src,
                                               unsigned short* __restrict__ dst) {
  const size_t i = ((size_t)blockIdx.x * 256 + threadIdx.x) * 8;
  const float4* s = reinterpret_cast<const float4*>(src + i);
  float4 x0 = s[0], x1 = s[1];
  int4 o = make_int4((int)pk2(x0.x, x0.y), (int)pk2(x0.z, x0.w),
                     (int)pk2(x1.x, x1.y), (int)pk2(x1.z, x1.w));
  *reinterpret_cast<int4*>(dst + i) = o;
}

// ---------------- Kernel 1: W [K,N] f32 -> Wt [N,K] bf16 ----------------
__global__ __launch_bounds__(256) void convW_k(const float* __restrict__ W,
                                               unsigned short* __restrict__ Wt) {
  __shared__ float tile[64][65];
  const int n0 = blockIdx.x * 64, k0 = blockIdx.y * 64;
  const int t = threadIdx.x;
  const int r = t >> 2, q = t & 3;
  const float4* src = reinterpret_cast<const float4*>(W + (size_t)(k0 + r) * NM + n0 + q * 16);
  float4 x0 = src[0], x1 = src[1], x2 = src[2], x3 = src[3];
  float* tr = &tile[r][q * 16];
  tr[0]=x0.x; tr[1]=x0.y; tr[2]=x0.z;  tr[3]=x0.w;
  tr[4]=x1.x; tr[5]=x1.y; tr[6]=x1.z;  tr[7]=x1.w;
  tr[8]=x2.x; tr[9]=x2.y; tr[10]=x2.z; tr[11]=x2.w;
  tr[12]=x3.x; tr[13]=x3.y; tr[14]=x3.z; tr[15]=x3.w;
  __syncthreads();
  unsigned int pk[8];
#pragma unroll
  for (int i = 0; i < 8; ++i)
    pk[i] = pk2(tile[q * 16 + 2 * i][r], tile[q * 16 + 2 * i + 1][r]);
  int4* dst = reinterpret_cast<int4*>(Wt + (size_t)(n0 + r) * NC + k0 + q * 16);
  dst[0] = make_int4((int)pk[0], (int)pk[1], (int)pk[2], (int)pk[3]);
  dst[1] = make_int4((int)pk[4], (int)pk[5], (int)pk[6], (int)pk[7]);
}

// ------- Kernel 2: 256x256-tile 8-phase bf16 MFMA GEMM (T2+T3+T4+T5)
//         + two-phase fused epilogue (e->LDS bf16, coalesced memry pass) -------
__global__ __launch_bounds__(512) void gemm_fused(
    const unsigned short* __restrict__ Abf, const float* __restrict__ memry,
    const unsigned short* __restrict__ Wt, const float* __restrict__ bvec,
    float* __restrict__ pdotg, float* __restrict__ pesqg,
    float* __restrict__ pmsqg, float* __restrict__ pmsg) {
  __shared__ __align__(16) unsigned short LDS[2][4][8192];  // 128 KiB
  const int bm = blockIdx.x, bn = blockIdx.y;
  const int row0 = bm * 256, col0 = bn * 256;
  const int t = threadIdx.x;
  const int wid = t >> 6, lane = t & 63;
  const int wr = wid >> 2, wc = wid & 3;          // 2 x 4 waves
  const int l15 = lane & 15, lg = lane >> 4;
  const int ga8 = (lg ^ ((l15 >> 1) & 3)) * 8;    // swizzled k-granule (halfwords)

  f32x4 acc[8][4];
#pragma unroll
  for (int mi = 0; mi < 8; ++mi)
#pragma unroll
    for (int ni = 0; ni < 4; ++ni) acc[mi][ni] = (f32x4){0.f, 0.f, 0.f, 0.f};

  // 32-bit LDS byte offsets for inline-asm ds_read.
  // Layout byte offset: SL*65536 + TY*16384 + row*64 + ga8*2.
  // A tiles: TY = S (0/1).  B tiles: TY = 2+S  ->  +32768 base (R7 bug: missing).
  const unsigned ldsbase =
      (unsigned)(uintptr_t)(__attribute__((address_space(3))) void*)&LDS[0][0][0];
  const unsigned abase = ldsbase + ((wr * 128 + l15) * 32 + ga8) * 2;
  const unsigned bbase = ldsbase + 32768 + ((wc * 64 + l15) * 32 + ga8) * 2;

  // staging source (pre-swizzled column granule; same for row and row+128)
  const int srow0 = t >> 2;
  const int sk8 = ((t & 3) ^ ((srow0 >> 1) & 3)) * 8;
  const unsigned short* gA = Abf + (size_t)(row0 + srow0) * NC + sk8;
  const unsigned short* gB = Wt + (size_t)(col0 + srow0) * NC + sk8;

#define STG(SL, TY, KT)                                                      \
  {                                                                          \
    const unsigned short* s0 = ((TY) <= 1 ? gA : gB) + (KT) * 64 + ((TY)&1) * 32; \
    gload_lds16(s0, &LDS[SL][TY][t * 8]);                                    \
    gload_lds16(s0 + (size_t)128 * NC, &LDS[SL][TY][t * 8 + 4096]);          \
  }
#define NOSTG
#define VM6 asm volatile("s_waitcnt vmcnt(6)" ::: "memory")
#define VM0 asm volatile("s_waitcnt vmcnt(0)" ::: "memory")
#define NOVM

  // phase: asm ds-reads -> stage issue -> [vmcnt] -> barrier -> lgkmcnt(0)
  //        -> sched_barrier -> MFMA cluster -> barrier
#define PH(SL, S, MH, RDB, STAGE, VM)                                        \
  {                                                                          \
    if (RDB) {                                                               \
      const unsigned ba = bbase + (SL)*65536 + (S)*16384;                    \
      DSR(b[0], ba, "0");    DSR(b[1], ba, "1024");                          \
      DSR(b[2], ba, "2048"); DSR(b[3], ba, "3072");                          \
    }                                                                        \
    const unsigned aa = abase + (SL)*65536 + (S)*16384 + (MH)*4096;          \
    DSR(a[0], aa, "0");    DSR(a[1], aa, "1024");                            \
    DSR(a[2], aa, "2048"); DSR(a[3], aa, "3072");                            \
    STAGE;                                                                   \
    VM;                                                                      \
    __builtin_amdgcn_s_barrier();                                            \
    asm volatile("s_waitcnt lgkmcnt(0)" ::: "memory");                       \
    __builtin_amdgcn_sched_barrier(0);                                       \
    __builtin_amdgcn_s_setprio(1);                                           \
    _Pragma("unroll") for (int mi = 0; mi < 4; ++mi)                         \
        _Pragma("unroll") for (int ni = 0; ni < 4; ++ni)                     \
            acc[(MH)*4 + mi][ni] = __builtin_amdgcn_mfma_f32_16x16x32_bf16(  \
                a[mi], b[ni], acc[(MH)*4 + mi][ni], 0, 0, 0);                \
    __builtin_amdgcn_s_setprio(0);                                           \
    __builtin_amdgcn_s_barrier();                                            \
    __builtin_amdgcn_sched_barrier(0);                                       \
  }

  // ---- prologue: K-tile 0 fully + K-tile 1 minus Ak1 (vmcnt(6) -> c0 landed)
  STG(0, 2, 0); STG(0, 0, 0); STG(0, 3, 0); STG(0, 1, 0);
  STG(1, 2, 1); STG(1, 0, 1); STG(1, 3, 1);
  VM6;
  __builtin_amdgcn_s_barrier();
  __builtin_amdgcn_sched_barrier(0);

  bf16x8 a[4], b[4];
  // ---- main loop: 7 iterations x 2 K-tiles (K-tiles 0..13 computed here)
  for (int it = 0; it < 7; ++it) {
    const int c1 = 2 * it + 1, c2 = 2 * it + 2, c3 = 2 * it + 3;
    PH(0, 0, 0, true,  STG(1, 1, c1), NOVM);  // ph1
    PH(0, 0, 1, false, STG(0, 2, c2), NOVM);  // ph2
    PH(0, 1, 0, true,  STG(0, 0, c2), NOVM);  // ph3
    PH(0, 1, 1, false, STG(0, 3, c2), VM6);   // ph4
    PH(1, 0, 0, true,  STG(0, 1, c2), NOVM);  // ph5
    PH(1, 0, 1, false, STG(1, 2, c3), NOVM);  // ph6
    PH(1, 1, 0, true,  STG(1, 0, c3), NOVM);  // ph7
    PH(1, 1, 1, false, STG(1, 3, c3), VM6);   // ph8
  }
  // ---- final iteration (K-tiles 14, 15): only Ak1(15) left to stage
  PH(0, 0, 0, true,  STG(1, 1, 15), NOVM);
  PH(0, 0, 1, false, NOSTG, NOVM);
  PH(0, 1, 0, true,  NOSTG, NOVM);
  PH(0, 1, 1, false, NOSTG, VM0);
  PH(1, 0, 0, true,  NOSTG, NOVM);
  PH(1, 0, 1, false, NOSTG, NOVM);
  PH(1, 1, 0, true,  NOSTG, NOVM);
  PH(1, 1, 1, false, NOSTG, NOVM);
#undef PH
#undef STG

  // ---- E1: e = exp(z + b) -> bf16 into LDS [256][256] (reuses staging LDS;
  //      safe: final phase barrier + lgkmcnt guarantee all reads consumed) ----
  unsigned short (*e_lds)[256] = reinterpret_cast<unsigned short(*)[256]>(&LDS[0][0][0]);
  float bv[4];
#pragma unroll
  for (int ni = 0; ni < 4; ++ni) bv[ni] = bvec[col0 + wc * 64 + ni * 16 + l15];
#pragma unroll
  for (int mi = 0; mi < 8; ++mi)
#pragma unroll
    for (int ni = 0; ni < 4; ++ni)
#pragma unroll
      for (int j = 0; j < 4; ++j) {
        const int rl = wr * 128 + mi * 16 + 4 * lg + j;
        const int cl = wc * 64 + ni * 16 + l15;
        e_lds[rl][cl] = f2bf(__expf(acc[mi][ni][j] + bv[ni]));
      }
  __syncthreads();

  // ---- E2: coalesced fused pass: per row, partials of e*m, e^2, m^2, m ----
  {
    const int halfl = lane >> 5, l31 = lane & 31;
    const int rbase = wid * 32;  // each wave owns 32 consecutive rows
#pragma unroll 4
    for (int i = 0; i < 16; ++i) {
      const int rl = rbase + 2 * i + halfl;
      const float4* mp = reinterpret_cast<const float4*>(
          memry + (size_t)(row0 + rl) * NM + col0 + l31 * 8);
      float4 m0 = mp[0], m1 = mp[1];
      bf16x8 ev = *reinterpret_cast<const bf16x8*>(&e_lds[rl][l31 * 8]);
      float mv[8] = {m0.x, m0.y, m0.z, m0.w, m1.x, m1.y, m1.z, m1.w};
      float pd = 0.f, pe = 0.f, pq = 0.f, pm = 0.f;
#pragma unroll
      for (int k = 0; k < 8; ++k) {
        float e = __uint_as_float(((unsigned int)(unsigned short)ev[k]) << 16);
        pd += e * mv[k]; pe += e * e; pq += mv[k] * mv[k]; pm += mv[k];
      }
#pragma unroll
      for (int s = 1; s < 32; s <<= 1) {
        pd += __shfl_xor(pd, s); pe += __shfl_xor(pe, s);
        pq += __shfl_xor(pq, s); pm += __shfl_xor(pm, s);
      }
      if (l31 == 0) {
        const int idx = (row0 + rl) * NCH + bn;
        pdotg[idx] = pd; pesqg[idx] = pe; pmsqg[idx] = pq; pmsg[idx] = pm;
      }
    }
  }
}

// ---------------- Kernel 3: reduce partials -> sims, msum ----------------
__global__ __launch_bounds__(256) void finalize_k(
    const float* __restrict__ pd, const float* __restrict__ pe,
    const float* __restrict__ pq, const float* __restrict__ pm,
    float* __restrict__ sims, float* __restrict__ mst) {
  const int r = blockIdx.x * 256 + threadIdx.x;
  float d = 0.f, e = 0.f, q = 0.f, m = 0.f;
#pragma unroll
  for (int i = 0; i < NCH; ++i) {
    d += pd[r * NCH + i];
    e += pe[r * NCH + i];
    q += pq[r * NCH + i];
    m += pm[r * NCH + i];
  }
  sims[r] = -d / (sqrtf(fmaxf(e, 1e-12f)) * sqrtf(fmaxf(q, 1e-12f)));
  mst[r] = m;
}

// ------------- Kernel 4: softmax over B=8192 + final scaling -------------
__global__ __launch_bounds__(1024) void softmax_out_k(
    const float* __restrict__ sims, const float* __restrict__ mst,
    float* __restrict__ out) {
  __shared__ float red[16];
  const int t = threadIdx.x;
  float v[8];
  float mx = -1e30f;
#pragma unroll
  for (int i = 0; i < 8; ++i) {
    v[i] = sims[t + i * 1024];
    mx = fmaxf(mx, v[i]);
  }
#pragma unroll
  for (int s = 1; s < 64; s <<= 1) mx = fmaxf(mx, __shfl_xor(mx, s));
  if ((t & 63) == 0) red[t >> 6] = mx;
  __syncthreads();
  float m2 = red[0];
#pragma unroll
  for (int i = 1; i < 16; ++i) m2 = fmaxf(m2, red[i]);
  mx = m2;
  float sum = 0.f;
#pragma unroll
  for (int i = 0; i < 8; ++i) sum += __expf(v[i] - mx);
#pragma unroll
  for (int s = 1; s < 64; s <<= 1) sum += __shfl_xor(sum, s);
  __syncthreads();
  if ((t & 63) == 0) red[t >> 6] = sum;
  __syncthreads();
  float s2 = 0.f;
#pragma unroll
  for (int i = 0; i < 16; ++i) s2 += red[i];
  const float inv = 1.0f / s2;
#pragma unroll
  for (int i = 0; i < 8; ++i)
    out[t + i * 1024] = __expf(v[i] - mx) * inv * mst[t + i * 1024];
}

extern "C" void kernel_launch(void* const* d_in, const int* in_sizes, int n_in,
                              void* d_out, int out_size, void* d_ws, size_t ws_size,
                              hipStream_t stream) {
  const float* memry = (const float*)d_in[0];  // [B, M]
  const float* co    = (const float*)d_in[1];  // [B, C]
  const float* W     = (const float*)d_in[2];  // [C, M]
  const float* bvec  = (const float*)d_in[3];  // [M]
  float* out = (float*)d_out;                  // [B]

  char* w = (char*)d_ws;
  unsigned short* Wt  = (unsigned short*)w;                       // 8 MiB
  unsigned short* Abf = Wt + (size_t)NM * NC;                     // 16 MiB
  float* pdot = (float*)(Abf + (size_t)NB * NC);                  // 8192*16 f32 each
  float* pesq = pdot + (size_t)NB * NCH;
  float* pmsq = pesq + (size_t)NB * NCH;
  float* pms  = pmsq + (size_t)NB * NCH;
  float* sims = pms  + (size_t)NB * NCH;
  float* mst  = sims + NB;

  convA_k<<<(size_t)NB * NC / (256 * 8), 256, 0, stream>>>(co, Abf);
  convW_k<<<dim3(NM / 64, NC / 64), 256, 0, stream>>>(W, Wt);
  gemm_fused<<<dim3(NB / 256, NM / 256), 512, 0, stream>>>(Abf, memry, Wt, bvec,
                                                           pdot, pesq, pmsq, pms);
  finalize_k<<<NB / 256, 256, 0, stream>>>(pdot, pesq, pmsq, pms, sims, mst);
  softmax_out_k<<<1, 1024, 0, stream>>>(sims, mst, out);
}